// Round 1
// baseline (7482.647 us; speedup 1.0000x reference)
//
#include <hip/hip_runtime.h>

#define TB 256

// ---------------- index-width detection (int32 vs int64 src/dst) -------------
__global__ void detect_idx_kernel(const int* __restrict__ s32, const int* __restrict__ d32,
                                  int nE, int* __restrict__ flag) {
    __shared__ int nz;
    if (threadIdx.x == 0) nz = 0;
    __syncthreads();
    int n = nE < 2048 ? nE : 2048;
    int local = 0;
    for (int i = threadIdx.x; i < n; i += blockDim.x) {
        if (s32[2 * i + 1] != 0 || d32[2 * i + 1] != 0) local = 1;
    }
    if (local) atomicOr(&nz, 1);
    __syncthreads();
    if (threadIdx.x == 0) *flag = (nz == 0) ? 1 : 0;   // 1 => indices are int64
}

__device__ __forceinline__ int load_idx(const void* p, int e, int is64) {
    return is64 ? (int)((const long long*)p)[e] : ((const int*)p)[e];
}

// ---------------- degree ----------------------------------------------------
__global__ void deg_count_kernel(const void* __restrict__ dst, const int* __restrict__ flag,
                                 float* __restrict__ deg, int nE) {
    int t = blockIdx.x * blockDim.x + threadIdx.x;
    if (t >= nE) return;
    int is64 = *flag;
    atomicAdd(&deg[load_idx(dst, t, is64)], 1.0f);
}

__global__ void deg_inv_kernel(float* __restrict__ deg, int n) {
    int t = blockIdx.x * blockDim.x + threadIdx.x;
    if (t < n) deg[t] = 1.0f / fmaxf(deg[t], 1.0f);
}

// ---------------- edge scatter-add (sum part of mean-aggregate) --------------
// one thread per (edge, 4-float chunk)
__global__ void scatter_add_kernel(const float4* __restrict__ x4,
                                   const void* __restrict__ src, const void* __restrict__ dst,
                                   const int* __restrict__ flag,
                                   float* __restrict__ agg, int nE, int f4shift) {
    int t = blockIdx.x * blockDim.x + threadIdx.x;
    int total = nE << f4shift;
    if (t >= total) return;
    int e = t >> f4shift;
    int c = t & ((1 << f4shift) - 1);
    int is64 = *flag;
    int s = load_idx(src, e, is64);
    int d = load_idx(dst, e, is64);
    float4 v = x4[((size_t)s << f4shift) + c];
    float* p = agg + ((size_t)d << (f4shift + 2)) + ((size_t)c << 2);
    atomicAdd(p + 0, v.x);
    atomicAdd(p + 1, v.y);
    atomicAdd(p + 2, v.z);
    atomicAdd(p + 3, v.w);
}

// ---------------- fused GEMM -------------------------------------------------
// out[row, c] = A[row,:] @ W[:, c]
//   (+ rs2[row] * (A2[row,:] @ W2[:, c]))        if A2      (layer 1 dual-GEMM)
//   (+ rsAdd[row] * aggAdd[row, c])              if aggAdd  (pre-transformed agg)
//   (+ bias[c])                                  if bias
//   relu if doRelu; if doConcat (requires K==N) also out[row, N+c] = A[row, c]
__global__ __launch_bounds__(TB) void gemm_fused_kernel(
        const float* __restrict__ A, const float* __restrict__ W,
        const float* __restrict__ A2, const float* __restrict__ W2,
        const float* __restrict__ rs2,
        const float* __restrict__ aggAdd, const float* __restrict__ rsAdd,
        const float* __restrict__ bias,
        float* __restrict__ out,
        int M, int K, int ncShift, int N, int ldout,
        int doRelu, int doConcat) {
    int t = blockIdx.x * blockDim.x + threadIdx.x;
    int row = t >> ncShift;
    if (row >= M) return;
    int c4 = (t & ((1 << ncShift) - 1)) << 2;

    const float* a = A + (size_t)row * K;
    float ax = 0.f, ay = 0.f, az = 0.f, aw = 0.f;
    for (int k = 0; k < K; k += 4) {
        float4 av = *(const float4*)(a + k);
        const float* wk = W + (size_t)k * N + c4;
        float4 w0 = *(const float4*)(wk);
        float4 w1 = *(const float4*)(wk + N);
        float4 w2 = *(const float4*)(wk + 2 * (size_t)N);
        float4 w3 = *(const float4*)(wk + 3 * (size_t)N);
        ax += av.x * w0.x + av.y * w1.x + av.z * w2.x + av.w * w3.x;
        ay += av.x * w0.y + av.y * w1.y + av.z * w2.y + av.w * w3.y;
        az += av.x * w0.z + av.y * w1.z + av.z * w2.z + av.w * w3.z;
        aw += av.x * w0.w + av.y * w1.w + av.z * w2.w + av.w * w3.w;
    }
    if (A2) {
        float bx = 0.f, by = 0.f, bz = 0.f, bw = 0.f;
        const float* a2 = A2 + (size_t)row * K;
        for (int k = 0; k < K; k += 4) {
            float4 av = *(const float4*)(a2 + k);
            const float* wk = W2 + (size_t)k * N + c4;
            float4 w0 = *(const float4*)(wk);
            float4 w1 = *(const float4*)(wk + N);
            float4 w2 = *(const float4*)(wk + 2 * (size_t)N);
            float4 w3 = *(const float4*)(wk + 3 * (size_t)N);
            bx += av.x * w0.x + av.y * w1.x + av.z * w2.x + av.w * w3.x;
            by += av.x * w0.y + av.y * w1.y + av.z * w2.y + av.w * w3.y;
            bz += av.x * w0.z + av.y * w1.z + av.z * w2.z + av.w * w3.z;
            bw += av.x * w0.w + av.y * w1.w + av.z * w2.w + av.w * w3.w;
        }
        float s = rs2[row];
        ax += s * bx; ay += s * by; az += s * bz; aw += s * bw;
    }
    if (aggAdd) {
        float s = rsAdd[row];
        float4 g = *(const float4*)(aggAdd + (size_t)row * N + c4);
        ax += s * g.x; ay += s * g.y; az += s * g.z; aw += s * g.w;
    }
    if (bias) {
        float4 bb = *(const float4*)(bias + c4);
        ax += bb.x; ay += bb.y; az += bb.z; aw += bb.w;
    }
    if (doRelu) {
        ax = fmaxf(ax, 0.f); ay = fmaxf(ay, 0.f);
        az = fmaxf(az, 0.f); aw = fmaxf(aw, 0.f);
    }
    float4 r = make_float4(ax, ay, az, aw);
    *(float4*)(out + (size_t)row * ldout + c4) = r;
    if (doConcat) {  // K == N in all concat layers
        float4 av = *(const float4*)(a + c4);
        *(float4*)(out + (size_t)row * ldout + N + c4) = av;
    }
}

// ---------------- host orchestration ----------------------------------------
static inline int cdiv_i(long long a, int b) { return (int)((a + b - 1) / b); }

static void launch_gemm(const float* A, const float* W,
                        const float* A2, const float* W2, const float* rs2,
                        const float* aggAdd, const float* rsAdd,
                        const float* bias, float* out,
                        int M, int K, int N, int ldout, int relu, int concat,
                        hipStream_t stream) {
    int ncShift = (N == 128) ? 5 : (N == 64) ? 4 : 3;  // N/4 = 32/16/8
    long long total = (long long)M << ncShift;
    hipLaunchKernelGGL(gemm_fused_kernel, dim3(cdiv_i(total, TB)), dim3(TB), 0, stream,
                       A, W, A2, W2, rs2, aggAdd, rsAdd, bias, out,
                       M, K, ncShift, N, ldout, relu, concat);
}

static void launch_scatter(const float* x, const void* src, const void* dst, const int* flag,
                           float* agg, int nE, int F, int M, hipStream_t stream) {
    int f4shift = (F == 64) ? 4 : 3;  // F/4 = 16 or 8
    hipMemsetAsync(agg, 0, (size_t)M * F * sizeof(float), stream);
    long long total = (long long)nE << f4shift;
    hipLaunchKernelGGL(scatter_add_kernel, dim3(cdiv_i(total, TB)), dim3(TB), 0, stream,
                       (const float4*)x, src, dst, flag, agg, nE, f4shift);
}

extern "C" void kernel_launch(void* const* d_in, const int* in_sizes, int n_in,
                              void* d_out, int out_size, void* d_ws, size_t ws_size,
                              hipStream_t stream) {
    const float* in_feat = (const float*)d_in[0];
    const void* src = d_in[1];
    const void* dst = d_in[2];
    const float* Ws1 = (const float*)d_in[3];  const float* Wn1 = (const float*)d_in[4];  const float* b1 = (const float*)d_in[5];
    const float* Ws2 = (const float*)d_in[6];  const float* Wn2 = (const float*)d_in[7];  const float* b2 = (const float*)d_in[8];
    const float* Ws3 = (const float*)d_in[9];  const float* Wn3 = (const float*)d_in[10]; const float* b3 = (const float*)d_in[11];
    const float* Ws4 = (const float*)d_in[12]; const float* Wn4 = (const float*)d_in[13]; const float* b4 = (const float*)d_in[14];
    const float* Ws5 = (const float*)d_in[15]; const float* Wn5 = (const float*)d_in[16]; const float* b5 = (const float*)d_in[17];
    const float* Ws6 = (const float*)d_in[18]; const float* Wn6 = (const float*)d_in[19]; const float* b6 = (const float*)d_in[20];

    const int M  = in_sizes[0] / 64;   // 100000 nodes
    const int nE = in_sizes[1];        // 1600000 edges

    // workspace layout (floats)
    float* ws      = (float*)d_ws;
    float* deg_inv = ws;                              // M
    float* P1      = deg_inv + M;                     // M*128  (h1, later h5)
    float* P2      = P1 + (size_t)M * 128;            // M*64   (h2, later h4)
    float* P3      = P2 + (size_t)M * 64;             // M*32   (h3)
    float* agg     = P3 + (size_t)M * 32;             // M*64
    float* ybuf    = agg + (size_t)M * 64;            // M*64
    int*   flag    = (int*)(ybuf + (size_t)M * 64);   // 1

    // index-width detect + degrees
    hipLaunchKernelGGL(detect_idx_kernel, dim3(1), dim3(TB), 0, stream,
                       (const int*)src, (const int*)dst, nE, flag);
    hipMemsetAsync(deg_inv, 0, (size_t)M * sizeof(float), stream);
    hipLaunchKernelGGL(deg_count_kernel, dim3(cdiv_i(nE, TB)), dim3(TB), 0, stream,
                       dst, flag, deg_inv, nE);
    hipLaunchKernelGGL(deg_inv_kernel, dim3(cdiv_i(M, TB)), dim3(TB), 0, stream, deg_inv, M);

    // ---- layer 1: 64 -> 128, relu.  aggregate x (64-wide), dual GEMM
    launch_scatter(in_feat, src, dst, flag, agg, nE, 64, M, stream);
    launch_gemm(in_feat, Ws1, agg, Wn1, deg_inv, nullptr, nullptr, b1, P1,
                M, 64, 128, 128, 1, 0, stream);

    // ---- layer 2: 128 -> 64, relu.  transform-first: y = h1 @ Wn2 (64-wide)
    launch_gemm(P1, Wn2, nullptr, nullptr, nullptr, nullptr, nullptr, nullptr, ybuf,
                M, 128, 64, 64, 0, 0, stream);
    launch_scatter(ybuf, src, dst, flag, agg, nE, 64, M, stream);
    launch_gemm(P1, Ws2, nullptr, nullptr, nullptr, agg, deg_inv, b2, P2,
                M, 128, 64, 64, 1, 0, stream);

    // ---- layer 3: 64 -> 32, relu
    launch_gemm(P2, Wn3, nullptr, nullptr, nullptr, nullptr, nullptr, nullptr, ybuf,
                M, 64, 32, 32, 0, 0, stream);
    launch_scatter(ybuf, src, dst, flag, agg, nE, 32, M, stream);
    launch_gemm(P2, Ws3, nullptr, nullptr, nullptr, agg, deg_inv, b3, P3,
                M, 64, 32, 32, 1, 0, stream);

    // ---- layer 4: 32 -> 32, relu, concat h3 -> h4 (64 wide) in P2
    launch_gemm(P3, Wn4, nullptr, nullptr, nullptr, nullptr, nullptr, nullptr, ybuf,
                M, 32, 32, 32, 0, 0, stream);
    launch_scatter(ybuf, src, dst, flag, agg, nE, 32, M, stream);
    launch_gemm(P3, Ws4, nullptr, nullptr, nullptr, agg, deg_inv, b4, P2,
                M, 32, 32, 64, 1, 1, stream);

    // ---- layer 5: 64 -> 64, relu, concat h4 -> h5 (128 wide) in P1
    launch_gemm(P2, Wn5, nullptr, nullptr, nullptr, nullptr, nullptr, nullptr, ybuf,
                M, 64, 64, 64, 0, 0, stream);
    launch_scatter(ybuf, src, dst, flag, agg, nE, 64, M, stream);
    launch_gemm(P2, Ws5, nullptr, nullptr, nullptr, agg, deg_inv, b5, P1,
                M, 64, 64, 128, 1, 1, stream);

    // ---- layer 6: 128 -> 64, no relu, to d_out
    launch_gemm(P1, Wn6, nullptr, nullptr, nullptr, nullptr, nullptr, nullptr, ybuf,
                M, 128, 64, 64, 0, 0, stream);
    launch_scatter(ybuf, src, dst, flag, agg, nE, 64, M, stream);
    launch_gemm(P1, Ws6, nullptr, nullptr, nullptr, agg, deg_inv, b6, (float*)d_out,
                M, 128, 64, 64, 0, 0, stream);
}

// Round 2
// 1603.601 us; speedup vs baseline: 4.6662x; 4.6662x over previous
//
#include <hip/hip_runtime.h>

#define TB 256
#define SCAN_TB 1024

// ---------------- index-width detection (int32 vs int64 src/dst) -------------
__global__ void detect_idx_kernel(const int* __restrict__ s32, const int* __restrict__ d32,
                                  int nE, int* __restrict__ flag) {
    __shared__ int nz;
    if (threadIdx.x == 0) nz = 0;
    __syncthreads();
    int n = nE < 2048 ? nE : 2048;
    int local = 0;
    for (int i = threadIdx.x; i < n; i += blockDim.x) {
        if (s32[2 * i + 1] != 0 || d32[2 * i + 1] != 0) local = 1;
    }
    if (local) atomicOr(&nz, 1);
    __syncthreads();
    if (threadIdx.x == 0) *flag = (nz == 0) ? 1 : 0;   // 1 => indices are int64
}

__device__ __forceinline__ int load_idx(const void* p, int e, int is64) {
    return is64 ? (int)((const long long*)p)[e] : ((const int*)p)[e];
}

// ---------------- CSR build --------------------------------------------------
__global__ void hist_kernel(const void* __restrict__ dst, const int* __restrict__ flag,
                            int* __restrict__ deg, int nE) {
    int t = blockIdx.x * blockDim.x + threadIdx.x;
    if (t >= nE) return;
    atomicAdd(&deg[load_idx(dst, t, *flag)], 1);
}

// single-block exclusive scan: deg[0..M-1] -> rowptr[0..M]
__global__ __launch_bounds__(SCAN_TB) void scan_kernel(const int* __restrict__ deg,
                                                       int* __restrict__ rowptr, int M) {
    __shared__ int sh[SCAN_TB];
    int tid = threadIdx.x;
    int C = (M + SCAN_TB - 1) / SCAN_TB;
    int lo = tid * C;
    int hi = lo + C < M ? lo + C : M;
    int sum = 0;
    for (int i = lo; i < hi; ++i) sum += deg[i];
    sh[tid] = sum;
    __syncthreads();
    // Hillis-Steele inclusive scan over sh
    for (int off = 1; off < SCAN_TB; off <<= 1) {
        int t = (tid >= off) ? sh[tid - off] : 0;
        __syncthreads();
        sh[tid] += t;
        __syncthreads();
    }
    int base = (tid == 0) ? 0 : sh[tid - 1];
    int run = base;
    for (int i = lo; i < hi; ++i) { rowptr[i] = run; run += deg[i]; }
    if (tid == SCAN_TB - 1) rowptr[M] = sh[SCAN_TB - 1];
}

__global__ void copy_cursor_kernel(const int* __restrict__ rowptr, int* __restrict__ cursor, int M) {
    int t = blockIdx.x * blockDim.x + threadIdx.x;
    if (t < M) cursor[t] = rowptr[t];
}

__global__ void fill_kernel(const void* __restrict__ src, const void* __restrict__ dst,
                            const int* __restrict__ flag,
                            int* __restrict__ cursor, int* __restrict__ col, int nE) {
    int t = blockIdx.x * blockDim.x + threadIdx.x;
    if (t >= nE) return;
    int is64 = *flag;
    int d = load_idx(dst, t, is64);
    int s = load_idx(src, t, is64);
    int pos = atomicAdd(&cursor[d], 1);
    col[pos] = s;
}

// ---------------- mean-aggregate via CSR gather ------------------------------
// group of (F/4) threads per node, float4 per thread
__global__ __launch_bounds__(TB) void gather_mean_kernel(
        const float4* __restrict__ x4, const int* __restrict__ col,
        const int* __restrict__ rowptr, float4* __restrict__ out4,
        int M, int gshift) {
    int t = blockIdx.x * blockDim.x + threadIdx.x;
    int node = t >> gshift;
    if (node >= M) return;
    int c4 = t & ((1 << gshift) - 1);
    int s = rowptr[node], e = rowptr[node + 1];
    float ax = 0.f, ay = 0.f, az = 0.f, aw = 0.f;
    for (int j = s; j < e; ++j) {
        int cs = col[j];
        float4 v = x4[((size_t)cs << gshift) + c4];
        ax += v.x; ay += v.y; az += v.z; aw += v.w;
    }
    float sc = 1.0f / fmaxf((float)(e - s), 1.0f);
    out4[((size_t)node << gshift) + c4] = make_float4(ax * sc, ay * sc, az * sc, aw * sc);
}

// ---------------- fused GEMM -------------------------------------------------
// out[row, c] = A[row,:] @ W[:, c]
//   (+ A2[row,:] @ W2[:, c])          if A2      (layer 1 dual-GEMM; agg pre-scaled)
//   (+ aggAdd[row, c])                if aggAdd  (pre-transformed mean agg)
//   (+ bias[c])                       if bias
//   relu if doRelu; if doConcat (requires K==N) also out[row, N+c] = A[row, c]
__global__ __launch_bounds__(TB) void gemm_fused_kernel(
        const float* __restrict__ A, const float* __restrict__ W,
        const float* __restrict__ A2, const float* __restrict__ W2,
        const float* __restrict__ aggAdd,
        const float* __restrict__ bias,
        float* __restrict__ out,
        int M, int K, int ncShift, int N, int ldout,
        int doRelu, int doConcat) {
    int t = blockIdx.x * blockDim.x + threadIdx.x;
    int row = t >> ncShift;
    if (row >= M) return;
    int c4 = (t & ((1 << ncShift) - 1)) << 2;

    const float* a = A + (size_t)row * K;
    float ax = 0.f, ay = 0.f, az = 0.f, aw = 0.f;
    for (int k = 0; k < K; k += 4) {
        float4 av = *(const float4*)(a + k);
        const float* wk = W + (size_t)k * N + c4;
        float4 w0 = *(const float4*)(wk);
        float4 w1 = *(const float4*)(wk + N);
        float4 w2 = *(const float4*)(wk + 2 * (size_t)N);
        float4 w3 = *(const float4*)(wk + 3 * (size_t)N);
        ax += av.x * w0.x + av.y * w1.x + av.z * w2.x + av.w * w3.x;
        ay += av.x * w0.y + av.y * w1.y + av.z * w2.y + av.w * w3.y;
        az += av.x * w0.z + av.y * w1.z + av.z * w2.z + av.w * w3.z;
        aw += av.x * w0.w + av.y * w1.w + av.z * w2.w + av.w * w3.w;
    }
    if (A2) {
        const float* a2 = A2 + (size_t)row * K;
        for (int k = 0; k < K; k += 4) {
            float4 av = *(const float4*)(a2 + k);
            const float* wk = W2 + (size_t)k * N + c4;
            float4 w0 = *(const float4*)(wk);
            float4 w1 = *(const float4*)(wk + N);
            float4 w2 = *(const float4*)(wk + 2 * (size_t)N);
            float4 w3 = *(const float4*)(wk + 3 * (size_t)N);
            ax += av.x * w0.x + av.y * w1.x + av.z * w2.x + av.w * w3.x;
            ay += av.x * w0.y + av.y * w1.y + av.z * w2.y + av.w * w3.y;
            az += av.x * w0.z + av.y * w1.z + av.z * w2.z + av.w * w3.z;
            aw += av.x * w0.w + av.y * w1.w + av.z * w2.w + av.w * w3.w;
        }
    }
    if (aggAdd) {
        float4 g = *(const float4*)(aggAdd + (size_t)row * N + c4);
        ax += g.x; ay += g.y; az += g.z; aw += g.w;
    }
    if (bias) {
        float4 bb = *(const float4*)(bias + c4);
        ax += bb.x; ay += bb.y; az += bb.z; aw += bb.w;
    }
    if (doRelu) {
        ax = fmaxf(ax, 0.f); ay = fmaxf(ay, 0.f);
        az = fmaxf(az, 0.f); aw = fmaxf(aw, 0.f);
    }
    *(float4*)(out + (size_t)row * ldout + c4) = make_float4(ax, ay, az, aw);
    if (doConcat) {  // K == N in all concat layers
        float4 av = *(const float4*)(a + c4);
        *(float4*)(out + (size_t)row * ldout + N + c4) = av;
    }
}

// ---------------- host orchestration ----------------------------------------
static inline int cdiv_i(long long a, int b) { return (int)((a + b - 1) / b); }

static void launch_gemm(const float* A, const float* W,
                        const float* A2, const float* W2,
                        const float* aggAdd, const float* bias, float* out,
                        int M, int K, int N, int ldout, int relu, int concat,
                        hipStream_t stream) {
    int ncShift = (N == 128) ? 5 : (N == 64) ? 4 : 3;  // N/4 = 32/16/8
    long long total = (long long)M << ncShift;
    hipLaunchKernelGGL(gemm_fused_kernel, dim3(cdiv_i(total, TB)), dim3(TB), 0, stream,
                       A, W, A2, W2, aggAdd, bias, out,
                       M, K, ncShift, N, ldout, relu, concat);
}

static void launch_gather(const float* x, const int* col, const int* rowptr,
                          float* agg, int F, int M, hipStream_t stream) {
    int gshift = (F == 64) ? 4 : 3;  // F/4 threads per node
    long long total = (long long)M << gshift;
    hipLaunchKernelGGL(gather_mean_kernel, dim3(cdiv_i(total, TB)), dim3(TB), 0, stream,
                       (const float4*)x, col, rowptr, (float4*)agg, M, gshift);
}

extern "C" void kernel_launch(void* const* d_in, const int* in_sizes, int n_in,
                              void* d_out, int out_size, void* d_ws, size_t ws_size,
                              hipStream_t stream) {
    const float* in_feat = (const float*)d_in[0];
    const void* src = d_in[1];
    const void* dst = d_in[2];
    const float* Ws1 = (const float*)d_in[3];  const float* Wn1 = (const float*)d_in[4];  const float* b1 = (const float*)d_in[5];
    const float* Ws2 = (const float*)d_in[6];  const float* Wn2 = (const float*)d_in[7];  const float* b2 = (const float*)d_in[8];
    const float* Ws3 = (const float*)d_in[9];  const float* Wn3 = (const float*)d_in[10]; const float* b3 = (const float*)d_in[11];
    const float* Ws4 = (const float*)d_in[12]; const float* Wn4 = (const float*)d_in[13]; const float* b4 = (const float*)d_in[14];
    const float* Ws5 = (const float*)d_in[15]; const float* Wn5 = (const float*)d_in[16]; const float* b5 = (const float*)d_in[17];
    const float* Ws6 = (const float*)d_in[18]; const float* Wn6 = (const float*)d_in[19]; const float* b6 = (const float*)d_in[20];

    const int M  = in_sizes[0] / 64;   // 100000 nodes
    const int nE = in_sizes[1];        // 1600000 edges

    // workspace layout
    float* ws   = (float*)d_ws;
    float* P1   = ws;                        // M*128  (h1, later h5)
    float* P2   = P1 + (size_t)M * 128;      // M*64   (h2, later h4)
    float* P3   = P2 + (size_t)M * 64;       // M*32   (h3)
    float* agg  = P3 + (size_t)M * 32;       // M*64
    float* ybuf = agg + (size_t)M * 64;      // M*64
    int* deg    = (int*)(ybuf + (size_t)M * 64);  // M ints (later cursor)
    int* rowptr = deg + M;                   // M+1 ints
    int* col    = rowptr + (M + 1);          // nE ints
    int* flag   = col + nE;                  // 1 int

    // ---- CSR build
    hipLaunchKernelGGL(detect_idx_kernel, dim3(1), dim3(TB), 0, stream,
                       (const int*)src, (const int*)dst, nE, flag);
    hipMemsetAsync(deg, 0, (size_t)M * sizeof(int), stream);
    hipLaunchKernelGGL(hist_kernel, dim3(cdiv_i(nE, TB)), dim3(TB), 0, stream,
                       dst, flag, deg, nE);
    hipLaunchKernelGGL(scan_kernel, dim3(1), dim3(SCAN_TB), 0, stream, deg, rowptr, M);
    hipLaunchKernelGGL(copy_cursor_kernel, dim3(cdiv_i(M, TB)), dim3(TB), 0, stream,
                       rowptr, deg, M);  // deg becomes cursor
    hipLaunchKernelGGL(fill_kernel, dim3(cdiv_i(nE, TB)), dim3(TB), 0, stream,
                       src, dst, flag, deg, col, nE);

    // ---- layer 1: 64 -> 128, relu.  agg = mean(in_feat), dual GEMM
    launch_gather(in_feat, col, rowptr, agg, 64, M, stream);
    launch_gemm(in_feat, Ws1, agg, Wn1, nullptr, b1, P1,
                M, 64, 128, 128, 1, 0, stream);

    // ---- layer 2: 128 -> 64, relu.  transform-first: y = h1 @ Wn2 (64-wide)
    launch_gemm(P1, Wn2, nullptr, nullptr, nullptr, nullptr, ybuf,
                M, 128, 64, 64, 0, 0, stream);
    launch_gather(ybuf, col, rowptr, agg, 64, M, stream);
    launch_gemm(P1, Ws2, nullptr, nullptr, agg, b2, P2,
                M, 128, 64, 64, 1, 0, stream);

    // ---- layer 3: 64 -> 32, relu
    launch_gemm(P2, Wn3, nullptr, nullptr, nullptr, nullptr, ybuf,
                M, 64, 32, 32, 0, 0, stream);
    launch_gather(ybuf, col, rowptr, agg, 32, M, stream);
    launch_gemm(P2, Ws3, nullptr, nullptr, agg, b3, P3,
                M, 64, 32, 32, 1, 0, stream);

    // ---- layer 4: 32 -> 32, relu, concat h3 -> h4 (64 wide) in P2
    launch_gemm(P3, Wn4, nullptr, nullptr, nullptr, nullptr, ybuf,
                M, 32, 32, 32, 0, 0, stream);
    launch_gather(ybuf, col, rowptr, agg, 32, M, stream);
    launch_gemm(P3, Ws4, nullptr, nullptr, agg, b4, P2,
                M, 32, 32, 64, 1, 1, stream);

    // ---- layer 5: 64 -> 64, relu, concat h4 -> h5 (128 wide) in P1
    launch_gemm(P2, Wn5, nullptr, nullptr, nullptr, nullptr, ybuf,
                M, 64, 64, 64, 0, 0, stream);
    launch_gather(ybuf, col, rowptr, agg, 64, M, stream);
    launch_gemm(P2, Ws5, nullptr, nullptr, agg, b5, P1,
                M, 64, 64, 128, 1, 1, stream);

    // ---- layer 6: 128 -> 64, no relu, to d_out
    launch_gemm(P1, Wn6, nullptr, nullptr, nullptr, nullptr, ybuf,
                M, 128, 64, 64, 0, 0, stream);
    launch_gather(ybuf, col, rowptr, agg, 64, M, stream);
    launch_gemm(P1, Ws6, nullptr, nullptr, agg, b6, (float*)d_out,
                M, 128, 64, 64, 0, 0, stream);
}

// Round 3
// 1301.012 us; speedup vs baseline: 5.7514x; 1.2326x over previous
//
#include <hip/hip_runtime.h>

#define TB 256
#define SCAN_TB 1024

// ---------------- index-width detection (int32 vs int64 src/dst) -------------
__global__ void detect_idx_kernel(const int* __restrict__ s32, const int* __restrict__ d32,
                                  int nE, int* __restrict__ flag) {
    __shared__ int nz;
    if (threadIdx.x == 0) nz = 0;
    __syncthreads();
    int n = nE < 2048 ? nE : 2048;
    int local = 0;
    for (int i = threadIdx.x; i < n; i += blockDim.x) {
        if (s32[2 * i + 1] != 0 || d32[2 * i + 1] != 0) local = 1;
    }
    if (local) atomicOr(&nz, 1);
    __syncthreads();
    if (threadIdx.x == 0) *flag = (nz == 0) ? 1 : 0;   // 1 => indices are int64
}

__device__ __forceinline__ int load_idx(const void* p, int e, int is64) {
    return is64 ? (int)((const long long*)p)[e] : ((const int*)p)[e];
}

// ---------------- CSR build --------------------------------------------------
__global__ void hist_kernel(const void* __restrict__ dst, const int* __restrict__ flag,
                            int* __restrict__ deg, int nE) {
    int t = blockIdx.x * blockDim.x + threadIdx.x;
    if (t >= nE) return;
    atomicAdd(&deg[load_idx(dst, t, *flag)], 1);
}

// single-block exclusive scan: deg[0..M-1] -> rowptr[0..M]
__global__ __launch_bounds__(SCAN_TB) void scan_kernel(const int* __restrict__ deg,
                                                       int* __restrict__ rowptr, int M) {
    __shared__ int sh[SCAN_TB];
    int tid = threadIdx.x;
    int C = (M + SCAN_TB - 1) / SCAN_TB;
    int lo = tid * C;
    int hi = lo + C < M ? lo + C : M;
    int sum = 0;
    for (int i = lo; i < hi; ++i) sum += deg[i];
    sh[tid] = sum;
    __syncthreads();
    for (int off = 1; off < SCAN_TB; off <<= 1) {
        int t = (tid >= off) ? sh[tid - off] : 0;
        __syncthreads();
        sh[tid] += t;
        __syncthreads();
    }
    int base = (tid == 0) ? 0 : sh[tid - 1];
    int run = base;
    for (int i = lo; i < hi; ++i) { rowptr[i] = run; run += deg[i]; }
    if (tid == SCAN_TB - 1) rowptr[M] = sh[SCAN_TB - 1];
}

__global__ void copy_cursor_kernel(const int* __restrict__ rowptr, int* __restrict__ cursor, int M) {
    int t = blockIdx.x * blockDim.x + threadIdx.x;
    if (t < M) cursor[t] = rowptr[t];
}

__global__ void fill_kernel(const void* __restrict__ src, const void* __restrict__ dst,
                            const int* __restrict__ flag,
                            int* __restrict__ cursor, int* __restrict__ col, int nE) {
    int t = blockIdx.x * blockDim.x + threadIdx.x;
    if (t >= nE) return;
    int is64 = *flag;
    int d = load_idx(dst, t, is64);
    int s = load_idx(src, t, is64);
    int pos = atomicAdd(&cursor[d], 1);
    col[pos] = s;
}

// ---------------- mean-aggregate via CSR gather ------------------------------
__global__ __launch_bounds__(TB) void gather_mean_kernel(
        const float4* __restrict__ x4, const int* __restrict__ col,
        const int* __restrict__ rowptr, float4* __restrict__ out4,
        int M, int gshift) {
    int t = blockIdx.x * blockDim.x + threadIdx.x;
    int node = t >> gshift;
    if (node >= M) return;
    int c4 = t & ((1 << gshift) - 1);
    int s = rowptr[node], e = rowptr[node + 1];
    float ax = 0.f, ay = 0.f, az = 0.f, aw = 0.f;
    for (int j = s; j < e; ++j) {
        int cs = col[j];
        float4 v = x4[((size_t)cs << gshift) + c4];
        ax += v.x; ay += v.y; az += v.z; aw += v.w;
    }
    float sc = 1.0f / fmaxf((float)(e - s), 1.0f);
    out4[((size_t)node << gshift) + c4] = make_float4(ax * sc, ay * sc, az * sc, aw * sc);
}

// ---------------- register-tiled fused GEMM ----------------------------------
// 256 threads = 32 row-groups x 8 col-groups. Thread: 4 rows x (N/8) cols.
// Block covers 128 rows x N cols.
// out[row,c] = A@W (+ A2@W2 if DUAL) (+ aggAdd) (+ bias), relu opt,
// concat opt (K==N): out[row, N+c] = A[row, c]
template<int K, int N, int DUAL>
__global__ __launch_bounds__(TB) void gemm_rt_kernel(
        const float* __restrict__ A, const float* __restrict__ W,
        const float* __restrict__ A2, const float* __restrict__ W2,
        const float* __restrict__ aggAdd, const float* __restrict__ bias,
        float* __restrict__ out, int M, int ldout, int doRelu, int doConcat) {
    constexpr int C = N / 8;
    constexpr int NC4 = C / 4;
    const int colg = threadIdx.x & 7;
    const int rowg = threadIdx.x >> 3;
    const int row0 = blockIdx.x * 128 + rowg * 4;
    if (row0 >= M) return;           // M % 4 == 0, thread's 4 rows all in or all out
    const int c0 = colg * C;

    float4 acc[4][NC4];
    #pragma unroll
    for (int r = 0; r < 4; ++r)
        #pragma unroll
        for (int j = 0; j < NC4; ++j) acc[r][j] = make_float4(0.f, 0.f, 0.f, 0.f);

    const float* a = A + (size_t)row0 * K;
    for (int k = 0; k < K; k += 4) {
        float4 av[4];
        #pragma unroll
        for (int r = 0; r < 4; ++r)
            av[r] = *(const float4*)(a + (size_t)r * K + k);
        #pragma unroll
        for (int kk = 0; kk < 4; ++kk) {
            const float* wrow = W + (size_t)(k + kk) * N + c0;
            #pragma unroll
            for (int j = 0; j < NC4; ++j) {
                float4 wv = *(const float4*)(wrow + 4 * j);
                #pragma unroll
                for (int r = 0; r < 4; ++r) {
                    float a_rk = ((const float*)&av[r])[kk];
                    acc[r][j].x += a_rk * wv.x;
                    acc[r][j].y += a_rk * wv.y;
                    acc[r][j].z += a_rk * wv.z;
                    acc[r][j].w += a_rk * wv.w;
                }
            }
        }
    }
    if (DUAL) {
        const float* a2 = A2 + (size_t)row0 * K;
        for (int k = 0; k < K; k += 4) {
            float4 av[4];
            #pragma unroll
            for (int r = 0; r < 4; ++r)
                av[r] = *(const float4*)(a2 + (size_t)r * K + k);
            #pragma unroll
            for (int kk = 0; kk < 4; ++kk) {
                const float* wrow = W2 + (size_t)(k + kk) * N + c0;
                #pragma unroll
                for (int j = 0; j < NC4; ++j) {
                    float4 wv = *(const float4*)(wrow + 4 * j);
                    #pragma unroll
                    for (int r = 0; r < 4; ++r) {
                        float a_rk = ((const float*)&av[r])[kk];
                        acc[r][j].x += a_rk * wv.x;
                        acc[r][j].y += a_rk * wv.y;
                        acc[r][j].z += a_rk * wv.z;
                        acc[r][j].w += a_rk * wv.w;
                    }
                }
            }
        }
    }

    #pragma unroll
    for (int r = 0; r < 4; ++r) {
        const int row = row0 + r;
        float* orow = out + (size_t)row * ldout;
        #pragma unroll
        for (int j = 0; j < NC4; ++j) {
            float4 v = acc[r][j];
            const int c = c0 + 4 * j;
            if (aggAdd) {
                float4 g = *(const float4*)(aggAdd + (size_t)row * N + c);
                v.x += g.x; v.y += g.y; v.z += g.z; v.w += g.w;
            }
            if (bias) {
                float4 bb = *(const float4*)(bias + c);
                v.x += bb.x; v.y += bb.y; v.z += bb.z; v.w += bb.w;
            }
            if (doRelu) {
                v.x = fmaxf(v.x, 0.f); v.y = fmaxf(v.y, 0.f);
                v.z = fmaxf(v.z, 0.f); v.w = fmaxf(v.w, 0.f);
            }
            *(float4*)(orow + c) = v;
            if (doConcat) {  // K == N in all concat layers
                float4 acopy = *(const float4*)(a + (size_t)r * K + c);
                *(float4*)(orow + N + c) = acopy;
            }
        }
    }
}

// ---------------- host orchestration ----------------------------------------
static inline int cdiv_i(long long a, int b) { return (int)((a + b - 1) / b); }

template<int K, int N, int DUAL>
static void launch_gemm(const float* A, const float* W,
                        const float* A2, const float* W2,
                        const float* aggAdd, const float* bias, float* out,
                        int M, int ldout, int relu, int concat, hipStream_t stream) {
    hipLaunchKernelGGL((gemm_rt_kernel<K, N, DUAL>), dim3(cdiv_i(M, 128)), dim3(TB), 0, stream,
                       A, W, A2, W2, aggAdd, bias, out, M, ldout, relu, concat);
}

static void launch_gather(const float* x, const int* col, const int* rowptr,
                          float* agg, int F, int M, hipStream_t stream) {
    int gshift = (F == 64) ? 4 : 3;
    long long total = (long long)M << gshift;
    hipLaunchKernelGGL(gather_mean_kernel, dim3(cdiv_i(total, TB)), dim3(TB), 0, stream,
                       (const float4*)x, col, rowptr, (float4*)agg, M, gshift);
}

extern "C" void kernel_launch(void* const* d_in, const int* in_sizes, int n_in,
                              void* d_out, int out_size, void* d_ws, size_t ws_size,
                              hipStream_t stream) {
    const float* in_feat = (const float*)d_in[0];
    const void* src = d_in[1];
    const void* dst = d_in[2];
    const float* Ws1 = (const float*)d_in[3];  const float* Wn1 = (const float*)d_in[4];  const float* b1 = (const float*)d_in[5];
    const float* Ws2 = (const float*)d_in[6];  const float* Wn2 = (const float*)d_in[7];  const float* b2 = (const float*)d_in[8];
    const float* Ws3 = (const float*)d_in[9];  const float* Wn3 = (const float*)d_in[10]; const float* b3 = (const float*)d_in[11];
    const float* Ws4 = (const float*)d_in[12]; const float* Wn4 = (const float*)d_in[13]; const float* b4 = (const float*)d_in[14];
    const float* Ws5 = (const float*)d_in[15]; const float* Wn5 = (const float*)d_in[16]; const float* b5 = (const float*)d_in[17];
    const float* Ws6 = (const float*)d_in[18]; const float* Wn6 = (const float*)d_in[19]; const float* b6 = (const float*)d_in[20];

    const int M  = in_sizes[0] / 64;   // 100000 nodes
    const int nE = in_sizes[1];        // 1600000 edges

    // workspace layout
    float* ws   = (float*)d_ws;
    float* P1   = ws;                        // M*128  (h1, later h5)
    float* P2   = P1 + (size_t)M * 128;      // M*64   (h2, later h4)
    float* P3   = P2 + (size_t)M * 64;       // M*32   (h3)
    float* agg  = P3 + (size_t)M * 32;       // M*64
    float* ybuf = agg + (size_t)M * 64;      // M*64
    int* deg    = (int*)(ybuf + (size_t)M * 64);  // M ints (later cursor)
    int* rowptr = deg + M;                   // M+1 ints
    int* col    = rowptr + (M + 1);          // nE ints
    int* flag   = col + nE;                  // 1 int

    // ---- CSR build
    hipLaunchKernelGGL(detect_idx_kernel, dim3(1), dim3(TB), 0, stream,
                       (const int*)src, (const int*)dst, nE, flag);
    hipMemsetAsync(deg, 0, (size_t)M * sizeof(int), stream);
    hipLaunchKernelGGL(hist_kernel, dim3(cdiv_i(nE, TB)), dim3(TB), 0, stream,
                       dst, flag, deg, nE);
    hipLaunchKernelGGL(scan_kernel, dim3(1), dim3(SCAN_TB), 0, stream, deg, rowptr, M);
    hipLaunchKernelGGL(copy_cursor_kernel, dim3(cdiv_i(M, TB)), dim3(TB), 0, stream,
                       rowptr, deg, M);  // deg becomes cursor
    hipLaunchKernelGGL(fill_kernel, dim3(cdiv_i(nE, TB)), dim3(TB), 0, stream,
                       src, dst, flag, deg, col, nE);

    // ---- layer 1: 64 -> 128, relu.  agg = mean(in_feat), dual GEMM
    launch_gather(in_feat, col, rowptr, agg, 64, M, stream);
    launch_gemm<64, 128, 1>(in_feat, Ws1, agg, Wn1, nullptr, b1, P1,
                            M, 128, 1, 0, stream);

    // ---- layer 2: 128 -> 64, relu.  transform-first: y = h1 @ Wn2 (64-wide)
    launch_gemm<128, 64, 0>(P1, Wn2, nullptr, nullptr, nullptr, nullptr, ybuf,
                            M, 64, 0, 0, stream);
    launch_gather(ybuf, col, rowptr, agg, 64, M, stream);
    launch_gemm<128, 64, 0>(P1, Ws2, nullptr, nullptr, agg, b2, P2,
                            M, 64, 1, 0, stream);

    // ---- layer 3: 64 -> 32, relu
    launch_gemm<64, 32, 0>(P2, Wn3, nullptr, nullptr, nullptr, nullptr, ybuf,
                           M, 32, 0, 0, stream);
    launch_gather(ybuf, col, rowptr, agg, 32, M, stream);
    launch_gemm<64, 32, 0>(P2, Ws3, nullptr, nullptr, agg, b3, P3,
                           M, 32, 1, 0, stream);

    // ---- layer 4: 32 -> 32, relu, concat h3 -> h4 (64 wide) in P2
    launch_gemm<32, 32, 0>(P3, Wn4, nullptr, nullptr, nullptr, nullptr, ybuf,
                           M, 32, 0, 0, stream);
    launch_gather(ybuf, col, rowptr, agg, 32, M, stream);
    launch_gemm<32, 32, 0>(P3, Ws4, nullptr, nullptr, agg, b4, P2,
                           M, 64, 1, 1, stream);

    // ---- layer 5: 64 -> 64, relu, concat h4 -> h5 (128 wide) in P1
    launch_gemm<64, 64, 0>(P2, Wn5, nullptr, nullptr, nullptr, nullptr, ybuf,
                           M, 64, 0, 0, stream);
    launch_gather(ybuf, col, rowptr, agg, 64, M, stream);
    launch_gemm<64, 64, 0>(P2, Ws5, nullptr, nullptr, agg, b5, P1,
                           M, 128, 1, 1, stream);

    // ---- layer 6: 128 -> 64, no relu, to d_out
    launch_gemm<128, 64, 0>(P1, Wn6, nullptr, nullptr, nullptr, nullptr, ybuf,
                            M, 64, 0, 0, stream);
    launch_gather(ybuf, col, rowptr, agg, 64, M, stream);
    launch_gemm<128, 64, 0>(P1, Ws6, nullptr, nullptr, agg, b6, (float*)d_out,
                            M, 64, 0, 0, stream);
}